// Round 16
// baseline (213.620 us; speedup 1.0000x reference)
//
#include <hip/hip_runtime.h>
#include <hip/hip_bf16.h>
#include <math.h>

typedef unsigned short u16;
typedef __attribute__((ext_vector_type(8))) __bf16 bf16x8;
typedef __attribute__((ext_vector_type(4))) float f32x4;

__device__ inline u16 f2bf(float f) {
  union { float f; unsigned u; } x; x.f = f;
  unsigned r = x.u + 0x7fffu + ((x.u >> 16) & 1u);
  return (u16)(r >> 16);
}

__device__ inline unsigned cvtpk(float lo, float hi) {
  unsigned r;
  asm("v_cvt_pk_bf16_f32 %0, %1, %2" : "=v"(r) : "v"(lo), "v"(hi));
  return r;
}

__device__ inline float fexp2(float x) {
  float r;
  asm("v_exp_f32 %0, %1" : "=v"(r) : "v"(x));
  return r;
}

__device__ inline void async16(const void* g, void* l) {
  __builtin_amdgcn_global_load_lds(
      (const __attribute__((address_space(1))) void*)g,
      (__attribute__((address_space(3))) void*)l, 16, 0, 0);
}

// ------------- fused cast f32 -> bf16, 32B/lane (hs | attn_w | proj_w) -----
__global__ __launch_bounds__(256) void cast3_kernel(
    const float* __restrict__ hs, const float* __restrict__ aw,
    const float* __restrict__ pw, u16* __restrict__ hs_o,
    u16* __restrict__ aw_o, u16* __restrict__ pw_o) {
  int blk = blockIdx.x;
  const float* in;
  u16* out;
  int i;
  if (blk < 4096) {
    in = hs; out = hs_o; i = blk * 256 + threadIdx.x;
  } else if (blk < 6400) {
    in = aw; out = aw_o; i = (blk - 4096) * 256 + threadIdx.x;
  } else {
    in = pw; out = pw_o; i = (blk - 6400) * 256 + threadIdx.x;
  }
#pragma unroll
  for (int p = 0; p < 2; ++p) {
    int q = i * 2 + p;
    float4 v = ((const float4*)in)[q];
    u16 o0 = f2bf(v.x), o1 = f2bf(v.y), o2 = f2bf(v.z), o3 = f2bf(v.w);
    unsigned lo = (unsigned)o0 | ((unsigned)o1 << 16);
    unsigned hi = (unsigned)o2 | ((unsigned)o3 << 16);
    ((uint2*)out)[q] = make_uint2(lo, hi);
  }
}

// ---------------- V transpose via LDS: vt[b][d][s] = qkv[b][s][2176+d] ------
__global__ __launch_bounds__(256) void vt_kernel(
    const u16* __restrict__ qkv, u16* __restrict__ vt) {
  __shared__ u16 tile[32][136];
  const int t = threadIdx.x;
  const int b = blockIdx.x >> 6;
  const int S0 = (blockIdx.x & 63) * 32;
  const int s_l = t >> 3, dg = t & 7;
  const u16* src = qkv + ((size_t)b * 2048 + S0 + s_l) * 2304 + 2176 + dg * 16;
  *(uint4*)&tile[s_l][dg * 16] = *(const uint4*)src;
  *(uint4*)&tile[s_l][dg * 16 + 8] = *(const uint4*)(src + 8);
  __syncthreads();
  const int d = t >> 1, sh = t & 1;
  u16 buf[16];
#pragma unroll
  for (int j = 0; j < 16; ++j) buf[j] = tile[sh * 16 + j][d];
  u16* dst = vt + ((size_t)b * 128 + d) * 2048 + S0 + sh * 16;
  *(uint4*)dst = *(uint4*)&buf[0];
  *(uint4*)(dst + 8) = *(uint4*)&buf[8];
}

// ---------------- GEMM: C[M][N] = A[M][K] * W[N][K]^T + bias ----------------
// 256x128 tile, 8 waves, BK=64, 3-buffer LDS ring (144KB), prefetch
// distance 2, COUNTED vmcnt(6) + raw s_barrier (T4: staging batches stay in
// flight across barriers; each gets a full K-step to land). Conflict-free
// XOR-swizzled layout with per-lane base + immediate ds_read offsets.
template <bool BF16OUT>
__global__ __launch_bounds__(512) void gemm_bt(
    const u16* __restrict__ A, const u16* __restrict__ Bw,
    const float* __restrict__ bias, void* __restrict__ Cout,
    int M, int N, int K, int qcols, float qscale) {
  __shared__ u16 As[3][256 * 64];  // 32KB per buffer
  __shared__ u16 Bs[3][128 * 64];  // 16KB per buffer
  const int t = threadIdx.x;
  const int w = t >> 6;
  const int lane = t & 63;
  const int lq = lane >> 4, lr = lane & 15;

  // XCD-aware swizzle: 8 chunks (2 cols x 4 rows of chunks)
  int bx = blockIdx.x, by = blockIdx.y;
  const int gx = gridDim.x, gy = gridDim.y;
  if ((gx & 1) == 0 && (gy & 3) == 0) {
    const int cw = gx >> 1, ch = gy >> 2;
    int id = by * gx + bx;
    int xcd = id & 7, j = id >> 3;
    bx = (xcd & 1) * cw + j % cw;
    by = (xcd >> 1) * ch + j / cw;
  }

  const long brow = (long)by * 256;
  const long bcol = (long)bx * 128;
  const int wr = (w >> 1) * 64;  // M-quadrant (0..192)
  const int wc = (w & 1) * 64;   // N-half (0/64)
  f32x4 acc[4][4] = {};

  // staging source pointers (swizzled chunk; advance 64 cols per stage call)
  const u16* pA[4];
  const u16* pB[2];
#pragma unroll
  for (int it = 0; it < 4; ++it) {
    int ci = it * 512 + t;
    int row = ci >> 3;
    int ch = (ci & 7) ^ (row & 7);
    pA[it] = A + (brow + row) * (long)K + ch * 8;
  }
#pragma unroll
  for (int it = 0; it < 2; ++it) {
    int ci = it * 512 + t;
    int row = ci >> 3;
    int ch = (ci & 7) ^ (row & 7);
    pB[it] = Bw + (bcol + row) * (long)K + ch * 8;
  }

  char* const A0 = (char*)&As[0][0];
  char* const B0 = (char*)&Bs[0][0];
  const int stB = t * 16;  // per-thread stage dest offset within buffer

  auto stageTo = [&](char* aAn, char* bAn) {
#pragma unroll
    for (int it = 0; it < 4; ++it) {
      async16(pA[it], aAn + it * 8192 + stB);
      pA[it] += 64;
    }
#pragma unroll
    for (int it = 0; it < 2; ++it) {
      async16(pB[it], bAn + it * 8192 + stB);
      pB[it] += 64;
    }
  };

  // per-lane read bases: byte(row, kb, lq) = row*128 + ((kb*4+lq)^(row&7))*16
  const int swz = ((lr & 4) << 4) + ((lq << 4) ^ ((lr & 3) << 4));
  const int aOff = (wr + lr) * 128 + swz;
  const int bOff = (wc + lr) * 128 + swz;
  const int dx = (swz ^ 64) - swz;  // kb0 -> kb1 delta (row*128 has no bit 6)

  auto computeF = [&](const char* aR, const char* bR) {
    bf16x8 af[4], bfr[4];
#pragma unroll
    for (int m = 0; m < 4; ++m) af[m] = *(const bf16x8*)(aR + m * 2048);
#pragma unroll
    for (int n = 0; n < 4; ++n) bfr[n] = *(const bf16x8*)(bR + n * 2048);
#pragma unroll
    for (int m = 0; m < 4; ++m)
#pragma unroll
      for (int n = 0; n < 4; ++n)
        acc[m][n] = __builtin_amdgcn_mfma_f32_16x16x32_bf16(
            af[m], bfr[n], acc[m][n], 0, 0, 0);
    const char* a1 = aR + dx;
    const char* b1 = bR + dx;
#pragma unroll
    for (int m = 0; m < 4; ++m) af[m] = *(const bf16x8*)(a1 + m * 2048);
#pragma unroll
    for (int n = 0; n < 4; ++n) bfr[n] = *(const bf16x8*)(b1 + n * 2048);
#pragma unroll
    for (int m = 0; m < 4; ++m)
#pragma unroll
      for (int n = 0; n < 4; ++n)
        acc[m][n] = __builtin_amdgcn_mfma_f32_16x16x32_bf16(
            af[m], bfr[n], acc[m][n], 0, 0, 0);
  };

  // rotating buffer pointers (read base / stage anchor per ring slot)
  const char* ar0 = A0 + aOff;
  const char* ar1 = A0 + 32768 + aOff;
  const char* ar2 = A0 + 65536 + aOff;
  const char* br0 = B0 + bOff;
  const char* br1 = B0 + 16384 + bOff;
  const char* br2 = B0 + 32768 + bOff;
  char* sa0 = A0;
  char* sa1 = A0 + 32768;
  char* sa2 = A0 + 65536;
  char* sb0 = B0;
  char* sb1 = B0 + 16384;
  char* sb2 = B0 + 32768;

  const int nst = K >> 6;
  stageTo(sa0, sb0);  // kt = 0
  stageTo(sa1, sb1);  // kt = 64
  asm volatile("s_waitcnt vmcnt(6)" ::: "memory");  // buffer 0 complete
  __builtin_amdgcn_s_barrier();

  for (int s = 0; s < nst; ++s) {
    const bool st = (s + 2 < nst);
    if (st) stageTo(sa2, sb2);  // kt = 64*(s+2)
    computeF(ar0, br0);
    if (st)
      asm volatile("s_waitcnt vmcnt(6) lgkmcnt(0)" ::: "memory");
    else
      asm volatile("s_waitcnt vmcnt(0) lgkmcnt(0)" ::: "memory");
    __builtin_amdgcn_s_barrier();
    const char* ta = ar0; ar0 = ar1; ar1 = ar2; ar2 = ta;
    const char* tb = br0; br0 = br1; br1 = br2; br2 = tb;
    char* tsa = sa0; sa0 = sa1; sa1 = sa2; sa2 = tsa;
    char* tsb = sb0; sb0 = sb1; sb1 = sb2; sb2 = tsb;
  }

#pragma unroll
  for (int m = 0; m < 4; ++m) {
    long row0 = brow + wr + m * 16 + lq * 4;
#pragma unroll
    for (int n = 0; n < 4; ++n) {
      long col = bcol + wc + n * 16 + lr;
      float bv = bias[col];
      float cs = (col < qcols) ? qscale : 1.f;
#pragma unroll
      for (int j = 0; j < 4; ++j) {
        float v = (acc[m][n][j] + bv) * cs;
        if (BF16OUT)
          ((u16*)Cout)[(row0 + j) * N + col] = f2bf(v);
        else
          ((float*)Cout)[(row0 + j) * N + col] = v;
      }
    }
  }
}

// ---------------- Flash attention (MQA, causal) ----------------
// r15 proven version (65.9 us): kappa-permuted K rows -> in-register P via
// cvt_pk (no Pl); V fragments preloaded after QK^T (LDS latency overlaps
// softmax); per-lane l partials reduced once in the epilogue.
__global__ __launch_bounds__(256, 2) void attn_kernel(
    const u16* __restrict__ qkv, const u16* __restrict__ vt,
    u16* __restrict__ ctx) {
  __shared__ u16 Kl[2][64 * 136];  // 272B stride, 17408B per buffer
  __shared__ u16 Vl[2][128 * 72];  // 144B stride, 18432B per buffer

  const int t = threadIdx.x;
  const int w = t >> 6;
  const int lane = t & 63;
  const int lq = lane >> 4, lr = lane & 15;
  const int lkey = lq * 4;
  const int kbase8 = lq << 3;
  const int bid = blockIdx.x;
  const int qtid = bid >> 5;
  const int qt = (qtid < 8) ? (15 - qtid) : (qtid - 8);  // heavy first
  const int hb = bid & 31;
  const int h = hb & 15;
  const int b = hb >> 4;
  const int s0w = qt * 128 + w * 32;
  const size_t qb = (size_t)b * 2048 * 2304;

  bf16x8 qg[2][4];
#pragma unroll
  for (int s = 0; s < 2; ++s)
#pragma unroll
    for (int kc = 0; kc < 4; ++kc)
      qg[s][kc] = *(const bf16x8*)(qkv + qb +
                                   (size_t)(s0w + s * 16 + lr) * 2304 +
                                   h * 128 + kc * 32 + lq * 8);

  const u16* kp[5];
  const u16* vp[5];
#pragma unroll
  for (int ii = 0; ii < 5; ++ii) {
    int I = 4 * ii + w;
    {
      int pp = I * 1024 + lane * 16;
      int row = pp / 272;
      int rem = pp - row * 272;
      int ch = (rem < 256) ? (rem >> 4) : 0;
      if (row > 63) row = 63;
      int g = row >> 4, lqr = row & 15;
      int key = ((g & 1) << 5) + ((lqr >> 2) << 3) + ((g >> 1) << 2) +
                (lqr & 3);
      kp[ii] = qkv + qb + (size_t)key * 2304 + 2048 + ch * 8;
    }
    {
      int pp = I * 1024 + lane * 16;
      int row = pp / 144;
      int rem = pp - row * 144;
      int ch = (rem < 128) ? (rem >> 4) : 0;
      if (row > 127) row = 127;
      vp[ii] = vt + ((size_t)b * 128 + row) * 2048 + ch * 8;
    }
  }
  char* const KlB = (char*)&Kl[0][0];
  char* const VlB = (char*)&Vl[0][0];

  auto stage = [&](int buf) {
    char* kd = KlB + buf * 17408;
    char* vd = VlB + buf * 18432;
#pragma unroll
    for (int ii = 0; ii < 5; ++ii) {
      int I = 4 * ii + w;
      if (I < 17) {
        async16(kp[ii], kd + I * 1024);
        kp[ii] += 64 * 2304;
      }
    }
#pragma unroll
    for (int ii = 0; ii < 5; ++ii) {
      int I = 4 * ii + w;
      if (I < 18) {
        async16(vp[ii], vd + I * 1024);
        vp[ii] += 64;
      }
    }
  };

  const int loK = lr * 272 + lq * 16;
  const int loV = lr * 144 + lq * 16;

  float mreg[2] = {-INFINITY, -INFINITY};
  float lreg[2] = {0.f, 0.f};
  f32x4 o[2][8] = {};
  const int ntiles = 2 * qt + 2;

  stage(0);
  __syncthreads();

  int cur = 0;
  for (int j2 = 0; j2 < ntiles; ++j2) {
    const int kvb = j2 * 64;
    if (j2 + 1 < ntiles) stage(cur ^ 1);
    if (kvb <= s0w + 31) {
      const char* KL = KlB + cur * 17408 + loK;
      const char* VL = VlB + cur * 18432 + loV;
      const bool maskT = (kvb + 63 > s0w);

      f32x4 sc[2][4] = {};
#pragma unroll
      for (int g = 0; g < 4; ++g)
#pragma unroll
        for (int kc = 0; kc < 4; ++kc) {
          bf16x8 kf = *(const bf16x8*)(KL + g * 4352 + kc * 64);
          sc[0][g] = __builtin_amdgcn_mfma_f32_16x16x32_bf16(kf, qg[0][kc],
                                                             sc[0][g], 0, 0, 0);
          sc[1][g] = __builtin_amdgcn_mfma_f32_16x16x32_bf16(kf, qg[1][kc],
                                                             sc[1][g], 0, 0, 0);
        }

      bf16x8 vf[16];
#pragma unroll
      for (int n = 0; n < 8; ++n) {
        vf[2 * n] = *(const bf16x8*)(VL + n * 2304);
        vf[2 * n + 1] = *(const bf16x8*)(VL + n * 2304 + 64);
      }

      bf16x8 pa[2][2];
#pragma unroll
      for (int s = 0; s < 2; ++s) {
        float vv[16];
#pragma unroll
        for (int uu = 0; uu < 16; ++uu) vv[uu] = sc[s][uu >> 2][uu & 3];
        if (maskT) {
          const int qrel = s0w + s * 16 + lr - kvb - kbase8;
#pragma unroll
          for (int g = 0; g < 4; ++g)
#pragma unroll
            for (int r = 0; r < 4; ++r)
              if (((g & 1) << 5) + ((g >> 1) << 2) + r > qrel)
                vv[g * 4 + r] = -INFINITY;
        }
        float mx = vv[0];
#pragma unroll
        for (int uu = 1; uu < 16; ++uu) mx = fmaxf(mx, vv[uu]);
        mx = fmaxf(mx, __shfl_xor(mx, 16));
        mx = fmaxf(mx, __shfl_xor(mx, 32));
        float mn = mreg[s];
        if (__any(mx > mn + 8.f)) {  // T13 defer-rescale
          float mu = fmaxf(mn, mx);
          float alpha = fexp2(mn - mu);
          mreg[s] = mu;
          mn = mu;
          lreg[s] *= alpha;
          float a0 = __shfl(alpha, lkey + 0);
          float a1 = __shfl(alpha, lkey + 1);
          float a2 = __shfl(alpha, lkey + 2);
          float a3 = __shfl(alpha, lkey + 3);
#pragma unroll
          for (int n = 0; n < 8; ++n) {
            o[s][n][0] *= a0;
            o[s][n][1] *= a1;
            o[s][n][2] *= a2;
            o[s][n][3] *= a3;
          }
        }
        float e[16];
        float rs = 0.f;
#pragma unroll
        for (int uu = 0; uu < 16; ++uu) {
          e[uu] = fexp2(vv[uu] - mn);
          rs += e[uu];
        }
        lreg[s] += rs;
        union { unsigned uw[4]; bf16x8 v; } pk;
#pragma unroll
        for (int kc = 0; kc < 2; ++kc) {
          pk.uw[0] = cvtpk(e[kc * 4 + 0], e[kc * 4 + 1]);
          pk.uw[1] = cvtpk(e[kc * 4 + 2], e[kc * 4 + 3]);
          pk.uw[2] = cvtpk(e[(kc + 2) * 4 + 0], e[(kc + 2) * 4 + 1]);
          pk.uw[3] = cvtpk(e[(kc + 2) * 4 + 2], e[(kc + 2) * 4 + 3]);
          pa[s][kc] = pk.v;
        }
      }

#pragma unroll
      for (int n = 0; n < 8; ++n) {
        o[0][n] = __builtin_amdgcn_mfma_f32_16x16x32_bf16(pa[0][0], vf[2 * n],
                                                          o[0][n], 0, 0, 0);
        o[0][n] = __builtin_amdgcn_mfma_f32_16x16x32_bf16(
            pa[0][1], vf[2 * n + 1], o[0][n], 0, 0, 0);
        o[1][n] = __builtin_amdgcn_mfma_f32_16x16x32_bf16(pa[1][0], vf[2 * n],
                                                          o[1][n], 0, 0, 0);
        o[1][n] = __builtin_amdgcn_mfma_f32_16x16x32_bf16(
            pa[1][1], vf[2 * n + 1], o[1][n], 0, 0, 0);
      }
    }
    __syncthreads();
    cur ^= 1;
  }

#pragma unroll
  for (int s = 0; s < 2; ++s) {
    float lsum = lreg[s];
    lsum += __shfl_xor(lsum, 16);
    lsum += __shfl_xor(lsum, 32);
    float inv = 1.f / lsum;
    float iv[4];
    iv[0] = __shfl(inv, lkey + 0);
    iv[1] = __shfl(inv, lkey + 1);
    iv[2] = __shfl(inv, lkey + 2);
    iv[3] = __shfl(inv, lkey + 3);
#pragma unroll
    for (int r = 0; r < 4; ++r) {
      size_t rowoff =
          ((size_t)b * 2048 + s0w + s * 16 + lkey + r) * 2048 + h * 128;
#pragma unroll
      for (int n = 0; n < 8; ++n)
        ctx[rowoff + n * 16 + lr] = f2bf(o[s][n][r] * iv[r]);
    }
  }
}

extern "C" void kernel_launch(void* const* d_in, const int* in_sizes, int n_in,
                              void* d_out, int out_size, void* d_ws,
                              size_t ws_size, hipStream_t stream) {
  (void)in_sizes; (void)n_in; (void)out_size; (void)ws_size;
  const float* hs = (const float*)d_in[0];
  const float* attn_w = (const float*)d_in[1];
  const float* attn_b = (const float*)d_in[2];
  const float* proj_w = (const float*)d_in[3];
  const float* proj_b = (const float*)d_in[4];
  float* out = (float*)d_out;

  u16* hs_b = (u16*)d_ws;                      // 4096*2048
  u16* aw_b = hs_b + (size_t)4096 * 2048;      // 2304*2048
  u16* pw_b = aw_b + (size_t)2304 * 2048;      // 2048*2048
  u16* qkv_b = pw_b + (size_t)2048 * 2048;     // 4096*2304
  u16* vt_b = qkv_b + (size_t)4096 * 2304;     // 2*128*2048
  u16* ctx_b = vt_b + (size_t)2 * 128 * 2048;  // 4096*2048

  const float qscale = 0.08838834764831845f * 1.4426950408889634f;

  cast3_kernel<<<8448, 256, 0, stream>>>(hs, attn_w, proj_w, hs_b, aw_b,
                                         pw_b);

  gemm_bt<true><<<dim3(18, 16), 512, 0, stream>>>(hs_b, aw_b, attn_b, qkv_b,
                                                  4096, 2304, 2048, 2048,
                                                  qscale);
  vt_kernel<<<128, 256, 0, stream>>>(qkv_b, vt_b);
  attn_kernel<<<512, 256, 0, stream>>>(qkv_b, vt_b, ctx_b);
  gemm_bt<false><<<dim3(16, 16), 512, 0, stream>>>(ctx_b, pw_b, proj_b, out,
                                                   4096, 2048, 2048, 0, 1.f);
}

// Round 17
// 182.038 us; speedup vs baseline: 1.1735x; 1.1735x over previous
//
#include <hip/hip_runtime.h>
#include <hip/hip_bf16.h>
#include <math.h>

typedef unsigned short u16;
typedef __attribute__((ext_vector_type(8))) __bf16 bf16x8;
typedef __attribute__((ext_vector_type(4))) float f32x4;

__device__ inline u16 f2bf(float f) {
  union { float f; unsigned u; } x; x.f = f;
  unsigned r = x.u + 0x7fffu + ((x.u >> 16) & 1u);
  return (u16)(r >> 16);
}

__device__ inline unsigned cvtpk(float lo, float hi) {
  unsigned r;
  asm("v_cvt_pk_bf16_f32 %0, %1, %2" : "=v"(r) : "v"(lo), "v"(hi));
  return r;
}

__device__ inline float fexp2(float x) {
  float r;
  asm("v_exp_f32 %0, %1" : "=v"(r) : "v"(x));
  return r;
}

__device__ inline void async16(const void* g, void* l) {
  __builtin_amdgcn_global_load_lds(
      (const __attribute__((address_space(1))) void*)g,
      (__attribute__((address_space(3))) void*)l, 16, 0, 0);
}

// ------------- fused cast f32 -> bf16, 32B/lane (hs | attn_w | proj_w) -----
__global__ __launch_bounds__(256) void cast3_kernel(
    const float* __restrict__ hs, const float* __restrict__ aw,
    const float* __restrict__ pw, u16* __restrict__ hs_o,
    u16* __restrict__ aw_o, u16* __restrict__ pw_o) {
  int blk = blockIdx.x;
  const float* in;
  u16* out;
  int i;
  if (blk < 4096) {
    in = hs; out = hs_o; i = blk * 256 + threadIdx.x;
  } else if (blk < 6400) {
    in = aw; out = aw_o; i = (blk - 4096) * 256 + threadIdx.x;
  } else {
    in = pw; out = pw_o; i = (blk - 6400) * 256 + threadIdx.x;
  }
#pragma unroll
  for (int p = 0; p < 2; ++p) {
    int q = i * 2 + p;
    float4 v = ((const float4*)in)[q];
    u16 o0 = f2bf(v.x), o1 = f2bf(v.y), o2 = f2bf(v.z), o3 = f2bf(v.w);
    unsigned lo = (unsigned)o0 | ((unsigned)o1 << 16);
    unsigned hi = (unsigned)o2 | ((unsigned)o3 << 16);
    ((uint2*)out)[q] = make_uint2(lo, hi);
  }
}

// ---------------- V transpose via LDS: vt[b][d][s] = qkv[b][s][2176+d] ------
__global__ __launch_bounds__(256) void vt_kernel(
    const u16* __restrict__ qkv, u16* __restrict__ vt) {
  __shared__ u16 tile[32][136];
  const int t = threadIdx.x;
  const int b = blockIdx.x >> 6;
  const int S0 = (blockIdx.x & 63) * 32;
  const int s_l = t >> 3, dg = t & 7;
  const u16* src = qkv + ((size_t)b * 2048 + S0 + s_l) * 2304 + 2176 + dg * 16;
  *(uint4*)&tile[s_l][dg * 16] = *(const uint4*)src;
  *(uint4*)&tile[s_l][dg * 16 + 8] = *(const uint4*)(src + 8);
  __syncthreads();
  const int d = t >> 1, sh = t & 1;
  u16 buf[16];
#pragma unroll
  for (int j = 0; j < 16; ++j) buf[j] = tile[sh * 16 + j][d];
  u16* dst = vt + ((size_t)b * 128 + d) * 2048 + S0 + sh * 16;
  *(uint4*)dst = *(uint4*)&buf[0];
  *(uint4*)(dst + 8) = *(uint4*)&buf[8];
}

// ---------------- GEMM: C[M][N] = A[M][K] * W[N][K]^T + bias ----------------
// r15 proven version: dbuf BK=64, one __syncthreads per K-step, XCD chunk
// swizzle, precomputed per-lane LDS read bases (ds_read_b128 = base+imm).
template <bool BF16OUT>
__global__ __launch_bounds__(256) void gemm_bt(
    const u16* __restrict__ A, const u16* __restrict__ Bw,
    const float* __restrict__ bias, void* __restrict__ Cout,
    int M, int N, int K, int qcols, float qscale) {
  __shared__ u16 As[2][128 * 64];
  __shared__ u16 Bs[2][128 * 64];
  const int t = threadIdx.x;
  const int w = t >> 6;
  const int lane = t & 63;
  const int lq = lane >> 4, lr = lane & 15;

  int bx = blockIdx.x, by = blockIdx.y;
  const int gx = gridDim.x, gy = gridDim.y;
  if ((gx & 1) == 0 && (gy & 3) == 0) {
    const int cw = gx >> 1, ch = gy >> 2;
    int id = by * gx + bx;
    int xcd = id & 7, j = id >> 3;
    bx = (xcd & 1) * cw + j % cw;
    by = (xcd >> 1) * ch + j / cw;
  }

  const long brow = (long)by * 128;
  const long bcol = (long)bx * 128;
  const int wr = (w >> 1) * 64, wc = (w & 1) * 64;
  f32x4 acc[4][4] = {};

  int rA[4], cA[4];
#pragma unroll
  for (int it = 0; it < 4; ++it) {
    int ci = it * 256 + t;
    rA[it] = ci >> 3;
    cA[it] = (ci & 7) ^ (rA[it] & 7);
  }

  char* const AsB = (char*)&As[0][0];
  char* const BsB = (char*)&Bs[0][0];

  auto stage = [&](int buf, int kt) {
    char* ad = AsB + buf * 16384;
    char* bd = BsB + buf * 16384;
#pragma unroll
    for (int it = 0; it < 4; ++it) {
      const u16* srcA = A + (brow + rA[it]) * (long)K + kt + cA[it] * 8;
      async16(srcA, ad + (it * 256 + w * 64) * 16);
      const u16* srcB = Bw + (bcol + rA[it]) * (long)K + kt + cA[it] * 8;
      async16(srcB, bd + (it * 256 + w * 64) * 16);
    }
  };

  const int swz = ((lr & 4) << 4) + ((lq << 4) ^ ((lr & 3) << 4));
  const int aB0 = (wr + lr) * 128 + swz;
  const int bB0 = (wc + lr) * 128 + swz;
  const char* const a00 = AsB + aB0;
  const char* const a01 = AsB + (aB0 ^ 64);
  const char* const a10 = AsB + 16384 + aB0;
  const char* const a11 = AsB + 16384 + (aB0 ^ 64);
  const char* const b00 = BsB + bB0;
  const char* const b01 = BsB + (bB0 ^ 64);
  const char* const b10 = BsB + 16384 + bB0;
  const char* const b11 = BsB + 16384 + (bB0 ^ 64);

  auto computeK = [&](const char* a0, const char* a1, const char* b0,
                      const char* b1) {
    bf16x8 af[4], bfr[4];
#pragma unroll
    for (int m = 0; m < 4; ++m) af[m] = *(const bf16x8*)(a0 + m * 2048);
#pragma unroll
    for (int n = 0; n < 4; ++n) bfr[n] = *(const bf16x8*)(b0 + n * 2048);
#pragma unroll
    for (int m = 0; m < 4; ++m)
#pragma unroll
      for (int n = 0; n < 4; ++n)
        acc[m][n] = __builtin_amdgcn_mfma_f32_16x16x32_bf16(
            af[m], bfr[n], acc[m][n], 0, 0, 0);
#pragma unroll
    for (int m = 0; m < 4; ++m) af[m] = *(const bf16x8*)(a1 + m * 2048);
#pragma unroll
    for (int n = 0; n < 4; ++n) bfr[n] = *(const bf16x8*)(b1 + n * 2048);
#pragma unroll
    for (int m = 0; m < 4; ++m)
#pragma unroll
      for (int n = 0; n < 4; ++n)
        acc[m][n] = __builtin_amdgcn_mfma_f32_16x16x32_bf16(
            af[m], bfr[n], acc[m][n], 0, 0, 0);
  };

  stage(0, 0);
  __syncthreads();

  for (int kt = 0; kt < K; kt += 128) {
    if (kt + 64 < K) stage(1, kt + 64);
    computeK(a00, a01, b00, b01);
    __syncthreads();
    if (kt + 128 < K) stage(0, kt + 128);
    computeK(a10, a11, b10, b11);
    __syncthreads();
  }

#pragma unroll
  for (int m = 0; m < 4; ++m) {
    long row0 = brow + wr + m * 16 + lq * 4;
#pragma unroll
    for (int n = 0; n < 4; ++n) {
      long col = bcol + wc + n * 16 + lr;
      float bv = bias[col];
      float cs = (col < qcols) ? qscale : 1.f;
#pragma unroll
      for (int j = 0; j < 4; ++j) {
        float v = (acc[m][n][j] + bv) * cs;
        if (BF16OUT)
          ((u16*)Cout)[(row0 + j) * N + col] = f2bf(v);
        else
          ((float*)Cout)[(row0 + j) * N + col] = v;
      }
    }
  }
}

// ---------------- Flash attention (MQA, causal) ----------------
// r15 base (65.9us). NEW this round: (1) ALTERNATING heavy/light block order
// so each CU's 2 resident blocks pair ~heavy+light (balanced ~34 tiles);
// (2) T5 setprio around MFMA clusters -- valid regime now: 2 INDEPENDENT
// blocks/CU (m191 attn regime), unlike r4's 1 lockstep block (m190 null).
__global__ __launch_bounds__(256, 2) void attn_kernel(
    const u16* __restrict__ qkv, const u16* __restrict__ vt,
    u16* __restrict__ ctx) {
  __shared__ u16 Kl[2][64 * 136];  // 272B stride, 17408B per buffer
  __shared__ u16 Vl[2][128 * 72];  // 144B stride, 18432B per buffer

  const int t = threadIdx.x;
  const int w = t >> 6;
  const int lane = t & 63;
  const int lq = lane >> 4, lr = lane & 15;
  const int lkey = lq * 4;
  const int kbase8 = lq << 3;
  const int bid = blockIdx.x;
  const int qtid = bid >> 5;
  // alternate heavy/light: 15,0,14,1,13,2,... -> co-resident pairs balance
  const int qt = (qtid & 1) ? (qtid >> 1) : (15 - (qtid >> 1));
  const int hb = bid & 31;
  const int h = hb & 15;
  const int b = hb >> 4;
  const int s0w = qt * 128 + w * 32;
  const size_t qb = (size_t)b * 2048 * 2304;

  bf16x8 qg[2][4];
#pragma unroll
  for (int s = 0; s < 2; ++s)
#pragma unroll
    for (int kc = 0; kc < 4; ++kc)
      qg[s][kc] = *(const bf16x8*)(qkv + qb +
                                   (size_t)(s0w + s * 16 + lr) * 2304 +
                                   h * 128 + kc * 32 + lq * 8);

  const u16* kp[5];
  const u16* vp[5];
#pragma unroll
  for (int ii = 0; ii < 5; ++ii) {
    int I = 4 * ii + w;
    {
      int pp = I * 1024 + lane * 16;
      int row = pp / 272;
      int rem = pp - row * 272;
      int ch = (rem < 256) ? (rem >> 4) : 0;
      if (row > 63) row = 63;
      int g = row >> 4, lqr = row & 15;
      int key = ((g & 1) << 5) + ((lqr >> 2) << 3) + ((g >> 1) << 2) +
                (lqr & 3);
      kp[ii] = qkv + qb + (size_t)key * 2304 + 2048 + ch * 8;
    }
    {
      int pp = I * 1024 + lane * 16;
      int row = pp / 144;
      int rem = pp - row * 144;
      int ch = (rem < 128) ? (rem >> 4) : 0;
      if (row > 127) row = 127;
      vp[ii] = vt + ((size_t)b * 128 + row) * 2048 + ch * 8;
    }
  }
  char* const KlB = (char*)&Kl[0][0];
  char* const VlB = (char*)&Vl[0][0];

  auto stage = [&](int buf) {
    char* kd = KlB + buf * 17408;
    char* vd = VlB + buf * 18432;
#pragma unroll
    for (int ii = 0; ii < 5; ++ii) {
      int I = 4 * ii + w;
      if (I < 17) {
        async16(kp[ii], kd + I * 1024);
        kp[ii] += 64 * 2304;
      }
    }
#pragma unroll
    for (int ii = 0; ii < 5; ++ii) {
      int I = 4 * ii + w;
      if (I < 18) {
        async16(vp[ii], vd + I * 1024);
        vp[ii] += 64;
      }
    }
  };

  const int loK = lr * 272 + lq * 16;
  const int loV = lr * 144 + lq * 16;

  float mreg[2] = {-INFINITY, -INFINITY};
  float lreg[2] = {0.f, 0.f};
  f32x4 o[2][8] = {};
  const int ntiles = 2 * qt + 2;

  stage(0);
  __syncthreads();

  int cur = 0;
  for (int j2 = 0; j2 < ntiles; ++j2) {
    const int kvb = j2 * 64;
    if (j2 + 1 < ntiles) stage(cur ^ 1);
    if (kvb <= s0w + 31) {
      const char* KL = KlB + cur * 17408 + loK;
      const char* VL = VlB + cur * 18432 + loV;
      const bool maskT = (kvb + 63 > s0w);

      f32x4 sc[2][4] = {};
      __builtin_amdgcn_s_setprio(1);
#pragma unroll
      for (int g = 0; g < 4; ++g)
#pragma unroll
        for (int kc = 0; kc < 4; ++kc) {
          bf16x8 kf = *(const bf16x8*)(KL + g * 4352 + kc * 64);
          sc[0][g] = __builtin_amdgcn_mfma_f32_16x16x32_bf16(kf, qg[0][kc],
                                                             sc[0][g], 0, 0, 0);
          sc[1][g] = __builtin_amdgcn_mfma_f32_16x16x32_bf16(kf, qg[1][kc],
                                                             sc[1][g], 0, 0, 0);
        }
      __builtin_amdgcn_s_setprio(0);

      bf16x8 vf[16];
#pragma unroll
      for (int n = 0; n < 8; ++n) {
        vf[2 * n] = *(const bf16x8*)(VL + n * 2304);
        vf[2 * n + 1] = *(const bf16x8*)(VL + n * 2304 + 64);
      }

      bf16x8 pa[2][2];
#pragma unroll
      for (int s = 0; s < 2; ++s) {
        float vv[16];
#pragma unroll
        for (int uu = 0; uu < 16; ++uu) vv[uu] = sc[s][uu >> 2][uu & 3];
        if (maskT) {
          const int qrel = s0w + s * 16 + lr - kvb - kbase8;
#pragma unroll
          for (int g = 0; g < 4; ++g)
#pragma unroll
            for (int r = 0; r < 4; ++r)
              if (((g & 1) << 5) + ((g >> 1) << 2) + r > qrel)
                vv[g * 4 + r] = -INFINITY;
        }
        float mx = vv[0];
#pragma unroll
        for (int uu = 1; uu < 16; ++uu) mx = fmaxf(mx, vv[uu]);
        mx = fmaxf(mx, __shfl_xor(mx, 16));
        mx = fmaxf(mx, __shfl_xor(mx, 32));
        float mn = mreg[s];
        if (__any(mx > mn + 8.f)) {  // T13 defer-rescale
          float mu = fmaxf(mn, mx);
          float alpha = fexp2(mn - mu);
          mreg[s] = mu;
          mn = mu;
          lreg[s] *= alpha;
          float a0 = __shfl(alpha, lkey + 0);
          float a1 = __shfl(alpha, lkey + 1);
          float a2 = __shfl(alpha, lkey + 2);
          float a3 = __shfl(alpha, lkey + 3);
#pragma unroll
          for (int n = 0; n < 8; ++n) {
            o[s][n][0] *= a0;
            o[s][n][1] *= a1;
            o[s][n][2] *= a2;
            o[s][n][3] *= a3;
          }
        }
        float e[16];
        float rs = 0.f;
#pragma unroll
        for (int uu = 0; uu < 16; ++uu) {
          e[uu] = fexp2(vv[uu] - mn);
          rs += e[uu];
        }
        lreg[s] += rs;
        union { unsigned uw[4]; bf16x8 v; } pk;
#pragma unroll
        for (int kc = 0; kc < 2; ++kc) {
          pk.uw[0] = cvtpk(e[kc * 4 + 0], e[kc * 4 + 1]);
          pk.uw[1] = cvtpk(e[kc * 4 + 2], e[kc * 4 + 3]);
          pk.uw[2] = cvtpk(e[(kc + 2) * 4 + 0], e[(kc + 2) * 4 + 1]);
          pk.uw[3] = cvtpk(e[(kc + 2) * 4 + 2], e[(kc + 2) * 4 + 3]);
          pa[s][kc] = pk.v;
        }
      }

      __builtin_amdgcn_s_setprio(1);
#pragma unroll
      for (int n = 0; n < 8; ++n) {
        o[0][n] = __builtin_amdgcn_mfma_f32_16x16x32_bf16(pa[0][0], vf[2 * n],
                                                          o[0][n], 0, 0, 0);
        o[0][n] = __builtin_amdgcn_mfma_f32_16x16x32_bf16(
            pa[0][1], vf[2 * n + 1], o[0][n], 0, 0, 0);
        o[1][n] = __builtin_amdgcn_mfma_f32_16x16x32_bf16(pa[1][0], vf[2 * n],
                                                          o[1][n], 0, 0, 0);
        o[1][n] = __builtin_amdgcn_mfma_f32_16x16x32_bf16(
            pa[1][1], vf[2 * n + 1], o[1][n], 0, 0, 0);
      }
      __builtin_amdgcn_s_setprio(0);
    }
    __syncthreads();
    cur ^= 1;
  }

#pragma unroll
  for (int s = 0; s < 2; ++s) {
    float lsum = lreg[s];
    lsum += __shfl_xor(lsum, 16);
    lsum += __shfl_xor(lsum, 32);
    float inv = 1.f / lsum;
    float iv[4];
    iv[0] = __shfl(inv, lkey + 0);
    iv[1] = __shfl(inv, lkey + 1);
    iv[2] = __shfl(inv, lkey + 2);
    iv[3] = __shfl(inv, lkey + 3);
#pragma unroll
    for (int r = 0; r < 4; ++r) {
      size_t rowoff =
          ((size_t)b * 2048 + s0w + s * 16 + lkey + r) * 2048 + h * 128;
#pragma unroll
      for (int n = 0; n < 8; ++n)
        ctx[rowoff + n * 16 + lr] = f2bf(o[s][n][r] * iv[r]);
    }
  }
}

extern "C" void kernel_launch(void* const* d_in, const int* in_sizes, int n_in,
                              void* d_out, int out_size, void* d_ws,
                              size_t ws_size, hipStream_t stream) {
  (void)in_sizes; (void)n_in; (void)out_size; (void)ws_size;
  const float* hs = (const float*)d_in[0];
  const float* attn_w = (const float*)d_in[1];
  const float* attn_b = (const float*)d_in[2];
  const float* proj_w = (const float*)d_in[3];
  const float* proj_b = (const float*)d_in[4];
  float* out = (float*)d_out;

  u16* hs_b = (u16*)d_ws;                      // 4096*2048
  u16* aw_b = hs_b + (size_t)4096 * 2048;      // 2304*2048
  u16* pw_b = aw_b + (size_t)2304 * 2048;      // 2048*2048
  u16* qkv_b = pw_b + (size_t)2048 * 2048;     // 4096*2304
  u16* vt_b = qkv_b + (size_t)4096 * 2304;     // 2*128*2048
  u16* ctx_b = vt_b + (size_t)2 * 128 * 2048;  // 4096*2048

  const float qscale = 0.08838834764831845f * 1.4426950408889634f;

  cast3_kernel<<<8448, 256, 0, stream>>>(hs, attn_w, proj_w, hs_b, aw_b,
                                         pw_b);

  gemm_bt<true><<<dim3(18, 32), 256, 0, stream>>>(hs_b, aw_b, attn_b, qkv_b,
                                                  4096, 2304, 2048, 2048,
                                                  qscale);
  vt_kernel<<<128, 256, 0, stream>>>(qkv_b, vt_b);
  attn_kernel<<<512, 256, 0, stream>>>(qkv_b, vt_b, ctx_b);
  gemm_bt<false><<<dim3(16, 32), 256, 0, stream>>>(ctx_b, pw_b, proj_b, out,
                                                   4096, 2048, 2048, 0, 1.f);
}

// Round 18
// 174.164 us; speedup vs baseline: 1.2265x; 1.0452x over previous
//
#include <hip/hip_runtime.h>
#include <hip/hip_bf16.h>
#include <math.h>

typedef unsigned short u16;
typedef __attribute__((ext_vector_type(8))) __bf16 bf16x8;
typedef __attribute__((ext_vector_type(4))) float f32x4;

__device__ inline u16 f2bf(float f) {
  union { float f; unsigned u; } x; x.f = f;
  unsigned r = x.u + 0x7fffu + ((x.u >> 16) & 1u);
  return (u16)(r >> 16);
}

__device__ inline unsigned cvtpk(float lo, float hi) {
  unsigned r;
  asm("v_cvt_pk_bf16_f32 %0, %1, %2" : "=v"(r) : "v"(lo), "v"(hi));
  return r;
}

__device__ inline float fexp2(float x) {
  float r;
  asm("v_exp_f32 %0, %1" : "=v"(r) : "v"(x));
  return r;
}

__device__ inline void async16(const void* g, void* l) {
  __builtin_amdgcn_global_load_lds(
      (const __attribute__((address_space(1))) void*)g,
      (__attribute__((address_space(3))) void*)l, 16, 0, 0);
}

// ------------- fused cast f32 -> bf16, 32B/lane (hs | attn_w | proj_w) -----
__global__ __launch_bounds__(256) void cast3_kernel(
    const float* __restrict__ hs, const float* __restrict__ aw,
    const float* __restrict__ pw, u16* __restrict__ hs_o,
    u16* __restrict__ aw_o, u16* __restrict__ pw_o) {
  int blk = blockIdx.x;
  const float* in;
  u16* out;
  int i;
  if (blk < 4096) {
    in = hs; out = hs_o; i = blk * 256 + threadIdx.x;
  } else if (blk < 6400) {
    in = aw; out = aw_o; i = (blk - 4096) * 256 + threadIdx.x;
  } else {
    in = pw; out = pw_o; i = (blk - 6400) * 256 + threadIdx.x;
  }
#pragma unroll
  for (int p = 0; p < 2; ++p) {
    int q = i * 2 + p;
    float4 v = ((const float4*)in)[q];
    u16 o0 = f2bf(v.x), o1 = f2bf(v.y), o2 = f2bf(v.z), o3 = f2bf(v.w);
    unsigned lo = (unsigned)o0 | ((unsigned)o1 << 16);
    unsigned hi = (unsigned)o2 | ((unsigned)o3 << 16);
    ((uint2*)out)[q] = make_uint2(lo, hi);
  }
}

// ---------------- V transpose via LDS: vt[b][d][s] = qkv[b][s][2176+d] ------
__global__ __launch_bounds__(256) void vt_kernel(
    const u16* __restrict__ qkv, u16* __restrict__ vt) {
  __shared__ u16 tile[32][136];
  const int t = threadIdx.x;
  const int b = blockIdx.x >> 6;
  const int S0 = (blockIdx.x & 63) * 32;
  const int s_l = t >> 3, dg = t & 7;
  const u16* src = qkv + ((size_t)b * 2048 + S0 + s_l) * 2304 + 2176 + dg * 16;
  *(uint4*)&tile[s_l][dg * 16] = *(const uint4*)src;
  *(uint4*)&tile[s_l][dg * 16 + 8] = *(const uint4*)(src + 8);
  __syncthreads();
  const int d = t >> 1, sh = t & 1;
  u16 buf[16];
#pragma unroll
  for (int j = 0; j < 16; ++j) buf[j] = tile[sh * 16 + j][d];
  u16* dst = vt + ((size_t)b * 128 + d) * 2048 + S0 + sh * 16;
  *(uint4*)dst = *(uint4*)&buf[0];
  *(uint4*)(dst + 8) = *(uint4*)&buf[8];
}

// ---------------- GEMM: C[M][N] = A[M][K] * W[N][K]^T + bias ----------------
// r15 proven version: dbuf BK=64, one __syncthreads per K-step, XCD chunk
// swizzle, precomputed per-lane LDS read bases (ds_read_b128 = base+imm).
template <bool BF16OUT>
__global__ __launch_bounds__(256) void gemm_bt(
    const u16* __restrict__ A, const u16* __restrict__ Bw,
    const float* __restrict__ bias, void* __restrict__ Cout,
    int M, int N, int K, int qcols, float qscale) {
  __shared__ u16 As[2][128 * 64];
  __shared__ u16 Bs[2][128 * 64];
  const int t = threadIdx.x;
  const int w = t >> 6;
  const int lane = t & 63;
  const int lq = lane >> 4, lr = lane & 15;

  int bx = blockIdx.x, by = blockIdx.y;
  const int gx = gridDim.x, gy = gridDim.y;
  if ((gx & 1) == 0 && (gy & 3) == 0) {
    const int cw = gx >> 1, ch = gy >> 2;
    int id = by * gx + bx;
    int xcd = id & 7, j = id >> 3;
    bx = (xcd & 1) * cw + j % cw;
    by = (xcd >> 1) * ch + j / cw;
  }

  const long brow = (long)by * 128;
  const long bcol = (long)bx * 128;
  const int wr = (w >> 1) * 64, wc = (w & 1) * 64;
  f32x4 acc[4][4] = {};

  int rA[4], cA[4];
#pragma unroll
  for (int it = 0; it < 4; ++it) {
    int ci = it * 256 + t;
    rA[it] = ci >> 3;
    cA[it] = (ci & 7) ^ (rA[it] & 7);
  }

  char* const AsB = (char*)&As[0][0];
  char* const BsB = (char*)&Bs[0][0];

  auto stage = [&](int buf, int kt) {
    char* ad = AsB + buf * 16384;
    char* bd = BsB + buf * 16384;
#pragma unroll
    for (int it = 0; it < 4; ++it) {
      const u16* srcA = A + (brow + rA[it]) * (long)K + kt + cA[it] * 8;
      async16(srcA, ad + (it * 256 + w * 64) * 16);
      const u16* srcB = Bw + (bcol + rA[it]) * (long)K + kt + cA[it] * 8;
      async16(srcB, bd + (it * 256 + w * 64) * 16);
    }
  };

  const int swz = ((lr & 4) << 4) + ((lq << 4) ^ ((lr & 3) << 4));
  const int aB0 = (wr + lr) * 128 + swz;
  const int bB0 = (wc + lr) * 128 + swz;
  const char* const a00 = AsB + aB0;
  const char* const a01 = AsB + (aB0 ^ 64);
  const char* const a10 = AsB + 16384 + aB0;
  const char* const a11 = AsB + 16384 + (aB0 ^ 64);
  const char* const b00 = BsB + bB0;
  const char* const b01 = BsB + (bB0 ^ 64);
  const char* const b10 = BsB + 16384 + bB0;
  const char* const b11 = BsB + 16384 + (bB0 ^ 64);

  auto computeK = [&](const char* a0, const char* a1, const char* b0,
                      const char* b1) {
    bf16x8 af[4], bfr[4];
#pragma unroll
    for (int m = 0; m < 4; ++m) af[m] = *(const bf16x8*)(a0 + m * 2048);
#pragma unroll
    for (int n = 0; n < 4; ++n) bfr[n] = *(const bf16x8*)(b0 + n * 2048);
#pragma unroll
    for (int m = 0; m < 4; ++m)
#pragma unroll
      for (int n = 0; n < 4; ++n)
        acc[m][n] = __builtin_amdgcn_mfma_f32_16x16x32_bf16(
            af[m], bfr[n], acc[m][n], 0, 0, 0);
#pragma unroll
    for (int m = 0; m < 4; ++m) af[m] = *(const bf16x8*)(a1 + m * 2048);
#pragma unroll
    for (int n = 0; n < 4; ++n) bfr[n] = *(const bf16x8*)(b1 + n * 2048);
#pragma unroll
    for (int m = 0; m < 4; ++m)
#pragma unroll
      for (int n = 0; n < 4; ++n)
        acc[m][n] = __builtin_amdgcn_mfma_f32_16x16x32_bf16(
            af[m], bfr[n], acc[m][n], 0, 0, 0);
  };

  stage(0, 0);
  __syncthreads();

  for (int kt = 0; kt < K; kt += 128) {
    if (kt + 64 < K) stage(1, kt + 64);
    computeK(a00, a01, b00, b01);
    __syncthreads();
    if (kt + 128 < K) stage(0, kt + 128);
    computeK(a10, a11, b10, b11);
    __syncthreads();
  }

#pragma unroll
  for (int m = 0; m < 4; ++m) {
    long row0 = brow + wr + m * 16 + lq * 4;
#pragma unroll
    for (int n = 0; n < 4; ++n) {
      long col = bcol + wc + n * 16 + lr;
      float bv = bias[col];
      float cs = (col < qcols) ? qscale : 1.f;
#pragma unroll
      for (int j = 0; j < 4; ++j) {
        float v = (acc[m][n][j] + bv) * cs;
        if (BF16OUT)
          ((u16*)Cout)[(row0 + j) * N + col] = f2bf(v);
        else
          ((float*)Cout)[(row0 + j) * N + col] = v;
      }
    }
  }
}

// ---------------- Flash attention (MQA, causal) ----------------
// r15 base (65.9us, heavy-first order, no setprio). NEW: per-half
// softmax->PV interleave -- PV-half(s) (16 MFMA) issues right after
// softmax(s), so softmax(s=1)'s serial VALU chain overlaps PV(s=0)'s
// MFMA drain (separate pipes). Pure reordering of proven code.
__global__ __launch_bounds__(256, 2) void attn_kernel(
    const u16* __restrict__ qkv, const u16* __restrict__ vt,
    u16* __restrict__ ctx) {
  __shared__ u16 Kl[2][64 * 136];  // 272B stride, 17408B per buffer
  __shared__ u16 Vl[2][128 * 72];  // 144B stride, 18432B per buffer

  const int t = threadIdx.x;
  const int w = t >> 6;
  const int lane = t & 63;
  const int lq = lane >> 4, lr = lane & 15;
  const int lkey = lq * 4;
  const int kbase8 = lq << 3;
  const int bid = blockIdx.x;
  const int qtid = bid >> 5;
  const int qt = (qtid < 8) ? (15 - qtid) : (qtid - 8);  // heavy first
  const int hb = bid & 31;
  const int h = hb & 15;
  const int b = hb >> 4;
  const int s0w = qt * 128 + w * 32;
  const size_t qb = (size_t)b * 2048 * 2304;

  bf16x8 qg[2][4];
#pragma unroll
  for (int s = 0; s < 2; ++s)
#pragma unroll
    for (int kc = 0; kc < 4; ++kc)
      qg[s][kc] = *(const bf16x8*)(qkv + qb +
                                   (size_t)(s0w + s * 16 + lr) * 2304 +
                                   h * 128 + kc * 32 + lq * 8);

  const u16* kp[5];
  const u16* vp[5];
#pragma unroll
  for (int ii = 0; ii < 5; ++ii) {
    int I = 4 * ii + w;
    {
      int pp = I * 1024 + lane * 16;
      int row = pp / 272;
      int rem = pp - row * 272;
      int ch = (rem < 256) ? (rem >> 4) : 0;
      if (row > 63) row = 63;
      int g = row >> 4, lqr = row & 15;
      int key = ((g & 1) << 5) + ((lqr >> 2) << 3) + ((g >> 1) << 2) +
                (lqr & 3);
      kp[ii] = qkv + qb + (size_t)key * 2304 + 2048 + ch * 8;
    }
    {
      int pp = I * 1024 + lane * 16;
      int row = pp / 144;
      int rem = pp - row * 144;
      int ch = (rem < 128) ? (rem >> 4) : 0;
      if (row > 127) row = 127;
      vp[ii] = vt + ((size_t)b * 128 + row) * 2048 + ch * 8;
    }
  }
  char* const KlB = (char*)&Kl[0][0];
  char* const VlB = (char*)&Vl[0][0];

  auto stage = [&](int buf) {
    char* kd = KlB + buf * 17408;
    char* vd = VlB + buf * 18432;
#pragma unroll
    for (int ii = 0; ii < 5; ++ii) {
      int I = 4 * ii + w;
      if (I < 17) {
        async16(kp[ii], kd + I * 1024);
        kp[ii] += 64 * 2304;
      }
    }
#pragma unroll
    for (int ii = 0; ii < 5; ++ii) {
      int I = 4 * ii + w;
      if (I < 18) {
        async16(vp[ii], vd + I * 1024);
        vp[ii] += 64;
      }
    }
  };

  const int loK = lr * 272 + lq * 16;
  const int loV = lr * 144 + lq * 16;

  float mreg[2] = {-INFINITY, -INFINITY};
  float lreg[2] = {0.f, 0.f};
  f32x4 o[2][8] = {};
  const int ntiles = 2 * qt + 2;

  stage(0);
  __syncthreads();

  int cur = 0;
  for (int j2 = 0; j2 < ntiles; ++j2) {
    const int kvb = j2 * 64;
    if (j2 + 1 < ntiles) stage(cur ^ 1);
    if (kvb <= s0w + 31) {
      const char* KL = KlB + cur * 17408 + loK;
      const char* VL = VlB + cur * 18432 + loV;
      const bool maskT = (kvb + 63 > s0w);

      f32x4 sc[2][4] = {};
#pragma unroll
      for (int g = 0; g < 4; ++g)
#pragma unroll
        for (int kc = 0; kc < 4; ++kc) {
          bf16x8 kf = *(const bf16x8*)(KL + g * 4352 + kc * 64);
          sc[0][g] = __builtin_amdgcn_mfma_f32_16x16x32_bf16(kf, qg[0][kc],
                                                             sc[0][g], 0, 0, 0);
          sc[1][g] = __builtin_amdgcn_mfma_f32_16x16x32_bf16(kf, qg[1][kc],
                                                             sc[1][g], 0, 0, 0);
        }

      bf16x8 vf[16];
#pragma unroll
      for (int n = 0; n < 8; ++n) {
        vf[2 * n] = *(const bf16x8*)(VL + n * 2304);
        vf[2 * n + 1] = *(const bf16x8*)(VL + n * 2304 + 64);
      }

#pragma unroll
      for (int s = 0; s < 2; ++s) {
        // ---- softmax(s) ----
        float vv[16];
#pragma unroll
        for (int uu = 0; uu < 16; ++uu) vv[uu] = sc[s][uu >> 2][uu & 3];
        if (maskT) {
          const int qrel = s0w + s * 16 + lr - kvb - kbase8;
#pragma unroll
          for (int g = 0; g < 4; ++g)
#pragma unroll
            for (int r = 0; r < 4; ++r)
              if (((g & 1) << 5) + ((g >> 1) << 2) + r > qrel)
                vv[g * 4 + r] = -INFINITY;
        }
        float mx = vv[0];
#pragma unroll
        for (int uu = 1; uu < 16; ++uu) mx = fmaxf(mx, vv[uu]);
        mx = fmaxf(mx, __shfl_xor(mx, 16));
        mx = fmaxf(mx, __shfl_xor(mx, 32));
        float mn = mreg[s];
        if (__any(mx > mn + 8.f)) {  // T13 defer-rescale
          float mu = fmaxf(mn, mx);
          float alpha = fexp2(mn - mu);
          mreg[s] = mu;
          mn = mu;
          lreg[s] *= alpha;
          float a0 = __shfl(alpha, lkey + 0);
          float a1 = __shfl(alpha, lkey + 1);
          float a2 = __shfl(alpha, lkey + 2);
          float a3 = __shfl(alpha, lkey + 3);
#pragma unroll
          for (int n = 0; n < 8; ++n) {
            o[s][n][0] *= a0;
            o[s][n][1] *= a1;
            o[s][n][2] *= a2;
            o[s][n][3] *= a3;
          }
        }
        float e[16];
        float rs = 0.f;
#pragma unroll
        for (int uu = 0; uu < 16; ++uu) {
          e[uu] = fexp2(vv[uu] - mn);
          rs += e[uu];
        }
        lreg[s] += rs;
        bf16x8 pa0, pa1;
        {
          union { unsigned uw[4]; bf16x8 v; } pk;
          pk.uw[0] = cvtpk(e[0], e[1]);
          pk.uw[1] = cvtpk(e[2], e[3]);
          pk.uw[2] = cvtpk(e[8], e[9]);
          pk.uw[3] = cvtpk(e[10], e[11]);
          pa0 = pk.v;
          pk.uw[0] = cvtpk(e[4], e[5]);
          pk.uw[1] = cvtpk(e[6], e[7]);
          pk.uw[2] = cvtpk(e[12], e[13]);
          pk.uw[3] = cvtpk(e[14], e[15]);
          pa1 = pk.v;
        }
        // ---- PV-half(s): 16 MFMA, overlaps next half's softmax VALU ----
#pragma unroll
        for (int n = 0; n < 8; ++n) {
          o[s][n] = __builtin_amdgcn_mfma_f32_16x16x32_bf16(pa0, vf[2 * n],
                                                            o[s][n], 0, 0, 0);
          o[s][n] = __builtin_amdgcn_mfma_f32_16x16x32_bf16(pa1, vf[2 * n + 1],
                                                            o[s][n], 0, 0, 0);
        }
      }
    }
    __syncthreads();
    cur ^= 1;
  }

#pragma unroll
  for (int s = 0; s < 2; ++s) {
    float lsum = lreg[s];
    lsum += __shfl_xor(lsum, 16);
    lsum += __shfl_xor(lsum, 32);
    float inv = 1.f / lsum;
    float iv[4];
    iv[0] = __shfl(inv, lkey + 0);
    iv[1] = __shfl(inv, lkey + 1);
    iv[2] = __shfl(inv, lkey + 2);
    iv[3] = __shfl(inv, lkey + 3);
#pragma unroll
    for (int r = 0; r < 4; ++r) {
      size_t rowoff =
          ((size_t)b * 2048 + s0w + s * 16 + lkey + r) * 2048 + h * 128;
#pragma unroll
      for (int n = 0; n < 8; ++n)
        ctx[rowoff + n * 16 + lr] = f2bf(o[s][n][r] * iv[r]);
    }
  }
}

extern "C" void kernel_launch(void* const* d_in, const int* in_sizes, int n_in,
                              void* d_out, int out_size, void* d_ws,
                              size_t ws_size, hipStream_t stream) {
  (void)in_sizes; (void)n_in; (void)out_size; (void)ws_size;
  const float* hs = (const float*)d_in[0];
  const float* attn_w = (const float*)d_in[1];
  const float* attn_b = (const float*)d_in[2];
  const float* proj_w = (const float*)d_in[3];
  const float* proj_b = (const float*)d_in[4];
  float* out = (float*)d_out;

  u16* hs_b = (u16*)d_ws;                      // 4096*2048
  u16* aw_b = hs_b + (size_t)4096 * 2048;      // 2304*2048
  u16* pw_b = aw_b + (size_t)2304 * 2048;      // 2048*2048
  u16* qkv_b = pw_b + (size_t)2048 * 2048;     // 4096*2304
  u16* vt_b = qkv_b + (size_t)4096 * 2304;     // 2*128*2048
  u16* ctx_b = vt_b + (size_t)2 * 128 * 2048;  // 4096*2048

  const float qscale = 0.08838834764831845f * 1.4426950408889634f;

  cast3_kernel<<<8448, 256, 0, stream>>>(hs, attn_w, proj_w, hs_b, aw_b,
                                         pw_b);

  gemm_bt<true><<<dim3(18, 32), 256, 0, stream>>>(hs_b, aw_b, attn_b, qkv_b,
                                                  4096, 2304, 2048, 2048,
                                                  qscale);
  vt_kernel<<<128, 256, 0, stream>>>(qkv_b, vt_b);
  attn_kernel<<<512, 256, 0, stream>>>(qkv_b, vt_b, ctx_b);
  gemm_bt<false><<<dim3(16, 32), 256, 0, stream>>>(ctx_b, pw_b, proj_b, out,
                                                   4096, 2048, 2048, 0, 1.f);
}

// Round 19
// 172.633 us; speedup vs baseline: 1.2374x; 1.0089x over previous
//
#include <hip/hip_runtime.h>
#include <hip/hip_bf16.h>
#include <math.h>

typedef unsigned short u16;
typedef __attribute__((ext_vector_type(8))) __bf16 bf16x8;
typedef __attribute__((ext_vector_type(4))) float f32x4;

__device__ inline u16 f2bf(float f) {
  union { float f; unsigned u; } x; x.f = f;
  unsigned r = x.u + 0x7fffu + ((x.u >> 16) & 1u);
  return (u16)(r >> 16);
}

__device__ inline unsigned cvtpk(float lo, float hi) {
  unsigned r;
  asm("v_cvt_pk_bf16_f32 %0, %1, %2" : "=v"(r) : "v"(lo), "v"(hi));
  return r;
}

__device__ inline float fexp2(float x) {
  float r;
  asm("v_exp_f32 %0, %1" : "=v"(r) : "v"(x));
  return r;
}

__device__ inline void async16(const void* g, void* l) {
  __builtin_amdgcn_global_load_lds(
      (const __attribute__((address_space(1))) void*)g,
      (__attribute__((address_space(3))) void*)l, 16, 0, 0);
}

// ------------- fused cast f32 -> bf16, 32B/lane (hs | attn_w | proj_w) -----
__global__ __launch_bounds__(256) void cast3_kernel(
    const float* __restrict__ hs, const float* __restrict__ aw,
    const float* __restrict__ pw, u16* __restrict__ hs_o,
    u16* __restrict__ aw_o, u16* __restrict__ pw_o) {
  int blk = blockIdx.x;
  const float* in;
  u16* out;
  int i;
  if (blk < 4096) {
    in = hs; out = hs_o; i = blk * 256 + threadIdx.x;
  } else if (blk < 6400) {
    in = aw; out = aw_o; i = (blk - 4096) * 256 + threadIdx.x;
  } else {
    in = pw; out = pw_o; i = (blk - 6400) * 256 + threadIdx.x;
  }
#pragma unroll
  for (int p = 0; p < 2; ++p) {
    int q = i * 2 + p;
    float4 v = ((const float4*)in)[q];
    u16 o0 = f2bf(v.x), o1 = f2bf(v.y), o2 = f2bf(v.z), o3 = f2bf(v.w);
    unsigned lo = (unsigned)o0 | ((unsigned)o1 << 16);
    unsigned hi = (unsigned)o2 | ((unsigned)o3 << 16);
    ((uint2*)out)[q] = make_uint2(lo, hi);
  }
}

// ---------------- GEMM: C[M][N] = A[M][K] * W[N][K]^T + bias ----------------
// r15 proven structure: dbuf BK=64, one __syncthreads per K-step, XCD chunk
// swizzle, precomputed per-lane LDS read bases (ds_read_b128 = base+imm).
// NEW: blocks covering cols [2176,2304) also write their acc TRANSPOSED to
// vtout (V panel) -- replaces the separate vt_kernel dispatch. Each (m,n)
// fragment = 4 consecutive-s values -> one uint2 store.
template <bool BF16OUT>
__global__ __launch_bounds__(256) void gemm_bt(
    const u16* __restrict__ A, const u16* __restrict__ Bw,
    const float* __restrict__ bias, void* __restrict__ Cout,
    u16* __restrict__ vtout, int M, int N, int K, int qcols, float qscale) {
  __shared__ u16 As[2][128 * 64];
  __shared__ u16 Bs[2][128 * 64];
  const int t = threadIdx.x;
  const int w = t >> 6;
  const int lane = t & 63;
  const int lq = lane >> 4, lr = lane & 15;

  int bx = blockIdx.x, by = blockIdx.y;
  const int gx = gridDim.x, gy = gridDim.y;
  if ((gx & 1) == 0 && (gy & 3) == 0) {
    const int cw = gx >> 1, ch = gy >> 2;
    int id = by * gx + bx;
    int xcd = id & 7, j = id >> 3;
    bx = (xcd & 1) * cw + j % cw;
    by = (xcd >> 1) * ch + j / cw;
  }

  const long brow = (long)by * 128;
  const long bcol = (long)bx * 128;
  const int wr = (w >> 1) * 64, wc = (w & 1) * 64;
  f32x4 acc[4][4] = {};

  int rA[4], cA[4];
#pragma unroll
  for (int it = 0; it < 4; ++it) {
    int ci = it * 256 + t;
    rA[it] = ci >> 3;
    cA[it] = (ci & 7) ^ (rA[it] & 7);
  }

  char* const AsB = (char*)&As[0][0];
  char* const BsB = (char*)&Bs[0][0];

  auto stage = [&](int buf, int kt) {
    char* ad = AsB + buf * 16384;
    char* bd = BsB + buf * 16384;
#pragma unroll
    for (int it = 0; it < 4; ++it) {
      const u16* srcA = A + (brow + rA[it]) * (long)K + kt + cA[it] * 8;
      async16(srcA, ad + (it * 256 + w * 64) * 16);
      const u16* srcB = Bw + (bcol + rA[it]) * (long)K + kt + cA[it] * 8;
      async16(srcB, bd + (it * 256 + w * 64) * 16);
    }
  };

  const int swz = ((lr & 4) << 4) + ((lq << 4) ^ ((lr & 3) << 4));
  const int aB0 = (wr + lr) * 128 + swz;
  const int bB0 = (wc + lr) * 128 + swz;
  const char* const a00 = AsB + aB0;
  const char* const a01 = AsB + (aB0 ^ 64);
  const char* const a10 = AsB + 16384 + aB0;
  const char* const a11 = AsB + 16384 + (aB0 ^ 64);
  const char* const b00 = BsB + bB0;
  const char* const b01 = BsB + (bB0 ^ 64);
  const char* const b10 = BsB + 16384 + bB0;
  const char* const b11 = BsB + 16384 + (bB0 ^ 64);

  auto computeK = [&](const char* a0, const char* a1, const char* b0,
                      const char* b1) {
    bf16x8 af[4], bfr[4];
#pragma unroll
    for (int m = 0; m < 4; ++m) af[m] = *(const bf16x8*)(a0 + m * 2048);
#pragma unroll
    for (int n = 0; n < 4; ++n) bfr[n] = *(const bf16x8*)(b0 + n * 2048);
#pragma unroll
    for (int m = 0; m < 4; ++m)
#pragma unroll
      for (int n = 0; n < 4; ++n)
        acc[m][n] = __builtin_amdgcn_mfma_f32_16x16x32_bf16(
            af[m], bfr[n], acc[m][n], 0, 0, 0);
#pragma unroll
    for (int m = 0; m < 4; ++m) af[m] = *(const bf16x8*)(a1 + m * 2048);
#pragma unroll
    for (int n = 0; n < 4; ++n) bfr[n] = *(const bf16x8*)(b1 + n * 2048);
#pragma unroll
    for (int m = 0; m < 4; ++m)
#pragma unroll
      for (int n = 0; n < 4; ++n)
        acc[m][n] = __builtin_amdgcn_mfma_f32_16x16x32_bf16(
            af[m], bfr[n], acc[m][n], 0, 0, 0);
  };

  stage(0, 0);
  __syncthreads();

  for (int kt = 0; kt < K; kt += 128) {
    if (kt + 64 < K) stage(1, kt + 64);
    computeK(a00, a01, b00, b01);
    __syncthreads();
    if (kt + 128 < K) stage(0, kt + 128);
    computeK(a10, a11, b10, b11);
    __syncthreads();
  }

#pragma unroll
  for (int m = 0; m < 4; ++m) {
    long row0 = brow + wr + m * 16 + lq * 4;
#pragma unroll
    for (int n = 0; n < 4; ++n) {
      long col = bcol + wc + n * 16 + lr;
      float bv = bias[col];
      float cs = (col < qcols) ? qscale : 1.f;
#pragma unroll
      for (int j = 0; j < 4; ++j) {
        float v = (acc[m][n][j] + bv) * cs;
        if (BF16OUT)
          ((u16*)Cout)[(row0 + j) * N + col] = f2bf(v);
        else
          ((float*)Cout)[(row0 + j) * N + col] = v;
      }
    }
  }

  // fused V-transpose: this block's cols are the V panel (d = col-2176)
  if (BF16OUT && vtout != nullptr && bcol == 2176) {
    const int bb = (int)(brow >> 11);
    const int s0 = (int)(brow & 2047) + wr + lq * 4;
#pragma unroll
    for (int m = 0; m < 4; ++m)
#pragma unroll
      for (int n = 0; n < 4; ++n) {
        int d = wc + n * 16 + lr;
        float bv = bias[2176 + d];
        union { u16 h[4]; uint2 u; } pk;
#pragma unroll
        for (int j = 0; j < 4; ++j) pk.h[j] = f2bf(acc[m][n][j] + bv);
        *(uint2*)(vtout + ((size_t)bb * 128 + d) * 2048 + s0 + m * 16) = pk.u;
      }
  }
}

// ---------------- Flash attention (MQA, causal) ----------------
// r18 proven version (65.5us): kappa-permuted K rows -> in-register P via
// cvt_pk (no Pl); V preload after QK^T; per-half softmax->PV interleave;
// per-lane l partials reduced once in the epilogue; heavy-first order
// (pairs heavy+light per CU under the c/c+256 dispatch pattern).
__global__ __launch_bounds__(256, 2) void attn_kernel(
    const u16* __restrict__ qkv, const u16* __restrict__ vt,
    u16* __restrict__ ctx) {
  __shared__ u16 Kl[2][64 * 136];  // 272B stride, 17408B per buffer
  __shared__ u16 Vl[2][128 * 72];  // 144B stride, 18432B per buffer

  const int t = threadIdx.x;
  const int w = t >> 6;
  const int lane = t & 63;
  const int lq = lane >> 4, lr = lane & 15;
  const int lkey = lq * 4;
  const int kbase8 = lq << 3;
  const int bid = blockIdx.x;
  const int qtid = bid >> 5;
  const int qt = (qtid < 8) ? (15 - qtid) : (qtid - 8);  // heavy first
  const int hb = bid & 31;
  const int h = hb & 15;
  const int b = hb >> 4;
  const int s0w = qt * 128 + w * 32;
  const size_t qb = (size_t)b * 2048 * 2304;

  bf16x8 qg[2][4];
#pragma unroll
  for (int s = 0; s < 2; ++s)
#pragma unroll
    for (int kc = 0; kc < 4; ++kc)
      qg[s][kc] = *(const bf16x8*)(qkv + qb +
                                   (size_t)(s0w + s * 16 + lr) * 2304 +
                                   h * 128 + kc * 32 + lq * 8);

  const u16* kp[5];
  const u16* vp[5];
#pragma unroll
  for (int ii = 0; ii < 5; ++ii) {
    int I = 4 * ii + w;
    {
      int pp = I * 1024 + lane * 16;
      int row = pp / 272;
      int rem = pp - row * 272;
      int ch = (rem < 256) ? (rem >> 4) : 0;
      if (row > 63) row = 63;
      int g = row >> 4, lqr = row & 15;
      int key = ((g & 1) << 5) + ((lqr >> 2) << 3) + ((g >> 1) << 2) +
                (lqr & 3);
      kp[ii] = qkv + qb + (size_t)key * 2304 + 2048 + ch * 8;
    }
    {
      int pp = I * 1024 + lane * 16;
      int row = pp / 144;
      int rem = pp - row * 144;
      int ch = (rem < 128) ? (rem >> 4) : 0;
      if (row > 127) row = 127;
      vp[ii] = vt + ((size_t)b * 128 + row) * 2048 + ch * 8;
    }
  }
  char* const KlB = (char*)&Kl[0][0];
  char* const VlB = (char*)&Vl[0][0];

  auto stage = [&](int buf) {
    char* kd = KlB + buf * 17408;
    char* vd = VlB + buf * 18432;
#pragma unroll
    for (int ii = 0; ii < 5; ++ii) {
      int I = 4 * ii + w;
      if (I < 17) {
        async16(kp[ii], kd + I * 1024);
        kp[ii] += 64 * 2304;
      }
    }
#pragma unroll
    for (int ii = 0; ii < 5; ++ii) {
      int I = 4 * ii + w;
      if (I < 18) {
        async16(vp[ii], vd + I * 1024);
        vp[ii] += 64;
      }
    }
  };

  const int loK = lr * 272 + lq * 16;
  const int loV = lr * 144 + lq * 16;

  float mreg[2] = {-INFINITY, -INFINITY};
  float lreg[2] = {0.f, 0.f};
  f32x4 o[2][8] = {};
  const int ntiles = 2 * qt + 2;

  stage(0);
  __syncthreads();

  int cur = 0;
  for (int j2 = 0; j2 < ntiles; ++j2) {
    const int kvb = j2 * 64;
    if (j2 + 1 < ntiles) stage(cur ^ 1);
    if (kvb <= s0w + 31) {
      const char* KL = KlB + cur * 17408 + loK;
      const char* VL = VlB + cur * 18432 + loV;
      const bool maskT = (kvb + 63 > s0w);

      f32x4 sc[2][4] = {};
#pragma unroll
      for (int g = 0; g < 4; ++g)
#pragma unroll
        for (int kc = 0; kc < 4; ++kc) {
          bf16x8 kf = *(const bf16x8*)(KL + g * 4352 + kc * 64);
          sc[0][g] = __builtin_amdgcn_mfma_f32_16x16x32_bf16(kf, qg[0][kc],
                                                             sc[0][g], 0, 0, 0);
          sc[1][g] = __builtin_amdgcn_mfma_f32_16x16x32_bf16(kf, qg[1][kc],
                                                             sc[1][g], 0, 0, 0);
        }

      bf16x8 vf[16];
#pragma unroll
      for (int n = 0; n < 8; ++n) {
        vf[2 * n] = *(const bf16x8*)(VL + n * 2304);
        vf[2 * n + 1] = *(const bf16x8*)(VL + n * 2304 + 64);
      }

#pragma unroll
      for (int s = 0; s < 2; ++s) {
        float vv[16];
#pragma unroll
        for (int uu = 0; uu < 16; ++uu) vv[uu] = sc[s][uu >> 2][uu & 3];
        if (maskT) {
          const int qrel = s0w + s * 16 + lr - kvb - kbase8;
#pragma unroll
          for (int g = 0; g < 4; ++g)
#pragma unroll
            for (int r = 0; r < 4; ++r)
              if (((g & 1) << 5) + ((g >> 1) << 2) + r > qrel)
                vv[g * 4 + r] = -INFINITY;
        }
        float mx = vv[0];
#pragma unroll
        for (int uu = 1; uu < 16; ++uu) mx = fmaxf(mx, vv[uu]);
        mx = fmaxf(mx, __shfl_xor(mx, 16));
        mx = fmaxf(mx, __shfl_xor(mx, 32));
        float mn = mreg[s];
        if (__any(mx > mn + 8.f)) {  // T13 defer-rescale
          float mu = fmaxf(mn, mx);
          float alpha = fexp2(mn - mu);
          mreg[s] = mu;
          mn = mu;
          lreg[s] *= alpha;
          float a0 = __shfl(alpha, lkey + 0);
          float a1 = __shfl(alpha, lkey + 1);
          float a2 = __shfl(alpha, lkey + 2);
          float a3 = __shfl(alpha, lkey + 3);
#pragma unroll
          for (int n = 0; n < 8; ++n) {
            o[s][n][0] *= a0;
            o[s][n][1] *= a1;
            o[s][n][2] *= a2;
            o[s][n][3] *= a3;
          }
        }
        float e[16];
        float rs = 0.f;
#pragma unroll
        for (int uu = 0; uu < 16; ++uu) {
          e[uu] = fexp2(vv[uu] - mn);
          rs += e[uu];
        }
        lreg[s] += rs;
        bf16x8 pa0, pa1;
        {
          union { unsigned uw[4]; bf16x8 v; } pk;
          pk.uw[0] = cvtpk(e[0], e[1]);
          pk.uw[1] = cvtpk(e[2], e[3]);
          pk.uw[2] = cvtpk(e[8], e[9]);
          pk.uw[3] = cvtpk(e[10], e[11]);
          pa0 = pk.v;
          pk.uw[0] = cvtpk(e[4], e[5]);
          pk.uw[1] = cvtpk(e[6], e[7]);
          pk.uw[2] = cvtpk(e[12], e[13]);
          pk.uw[3] = cvtpk(e[14], e[15]);
          pa1 = pk.v;
        }
#pragma unroll
        for (int n = 0; n < 8; ++n) {
          o[s][n] = __builtin_amdgcn_mfma_f32_16x16x32_bf16(pa0, vf[2 * n],
                                                            o[s][n], 0, 0, 0);
          o[s][n] = __builtin_amdgcn_mfma_f32_16x16x32_bf16(pa1, vf[2 * n + 1],
                                                            o[s][n], 0, 0, 0);
        }
      }
    }
    __syncthreads();
    cur ^= 1;
  }

#pragma unroll
  for (int s = 0; s < 2; ++s) {
    float lsum = lreg[s];
    lsum += __shfl_xor(lsum, 16);
    lsum += __shfl_xor(lsum, 32);
    float inv = 1.f / lsum;
    float iv[4];
    iv[0] = __shfl(inv, lkey + 0);
    iv[1] = __shfl(inv, lkey + 1);
    iv[2] = __shfl(inv, lkey + 2);
    iv[3] = __shfl(inv, lkey + 3);
#pragma unroll
    for (int r = 0; r < 4; ++r) {
      size_t rowoff =
          ((size_t)b * 2048 + s0w + s * 16 + lkey + r) * 2048 + h * 128;
#pragma unroll
      for (int n = 0; n < 8; ++n)
        ctx[rowoff + n * 16 + lr] = f2bf(o[s][n][r] * iv[r]);
    }
  }
}

extern "C" void kernel_launch(void* const* d_in, const int* in_sizes, int n_in,
                              void* d_out, int out_size, void* d_ws,
                              size_t ws_size, hipStream_t stream) {
  (void)in_sizes; (void)n_in; (void)out_size; (void)ws_size;
  const float* hs = (const float*)d_in[0];
  const float* attn_w = (const float*)d_in[1];
  const float* attn_b = (const float*)d_in[2];
  const float* proj_w = (const float*)d_in[3];
  const float* proj_b = (const float*)d_in[4];
  float* out = (float*)d_out;

  u16* hs_b = (u16*)d_ws;                      // 4096*2048
  u16* aw_b = hs_b + (size_t)4096 * 2048;      // 2304*2048
  u16* pw_b = aw_b + (size_t)2304 * 2048;      // 2048*2048
  u16* qkv_b = pw_b + (size_t)2048 * 2048;     // 4096*2304
  u16* vt_b = qkv_b + (size_t)4096 * 2304;     // 2*128*2048
  u16* ctx_b = vt_b + (size_t)2 * 128 * 2048;  // 4096*2048

  const float qscale = 0.08838834764831845f * 1.4426950408889634f;

  cast3_kernel<<<8448, 256, 0, stream>>>(hs, attn_w, proj_w, hs_b, aw_b,
                                         pw_b);

  gemm_bt<true><<<dim3(18, 32), 256, 0, stream>>>(hs_b, aw_b, attn_b, qkv_b,
                                                  vt_b, 4096, 2304, 2048,
                                                  2048, qscale);
  attn_kernel<<<512, 256, 0, stream>>>(qkv_b, vt_b, ctx_b);
  gemm_bt<false><<<dim3(16, 32), 256, 0, stream>>>(ctx_b, pw_b, proj_b, out,
                                                   nullptr, 4096, 2048, 2048,
                                                   0, 1.f);
}